// Round 1
// baseline (61.616 us; speedup 1.0000x reference)
//
#include <hip/hip_runtime.h>
#include <hip/hip_fp16.h>

typedef _Float16 half8 __attribute__((ext_vector_type(8)));
typedef float f32x4 __attribute__((ext_vector_type(4)));

// ---------------- workspace (d_ws) layout, bytes ----------------
// w0t : 13 K-tiles x [128 n][64 k] fp16, byte ^= ((n&7)<<4) swizzle : 13*16384
// w1p : [32 n][128 k] fp16, same swizzle (row stride 256B)          : 8192
// small (fp32): w3[22*32] | w5[21*24] | w7[10*24] | b3[24] | b5[24]
#define W0T_OFF   0
#define W1P_OFF   (13 * 16384)            // 212992
#define SW_OFF    (W1P_OFF + 8192)        // 221184
#define SW_BYTES  (2816 + 2016 + 960 + 96 + 96)   // 5984
#define WS_TOTAL  (SW_OFF + SW_BYTES)     // 227168

// ---------------- LDS map, bytes ----------------
#define L_XS   0        // [128][64] f16 swizzled (16384)  phase 0
#define L_WS   16384    // [128][64] f16 swizzled (16384)  phase 0
#define L_H0   0        // [128][128] f16 swizzled (32768) phases 1-2 (reuses XS+WS)
#define L_H1   32768    // [128][32] f16 swizzled (8192)
#define L_W1   40960    // [32][128] f16 swizzled (8192)
#define L_SW   49152    // 5984 fp32 small weights
#define L_H3   0        // [128][25] f32 (12800)           phase 3 (reuses H0)
#define L_H5   12800    // [128][25] f32 (12800)
#define LDS_BYTES 55136

// ============ prep: convert/pad/pre-swizzle weights into ws ============
__global__ void prep_weights(const float* __restrict__ w0,
                             const float* __restrict__ w1,
                             const float* __restrict__ w3,
                             const float* __restrict__ b3,
                             const float* __restrict__ w5,
                             const float* __restrict__ b5,
                             const float* __restrict__ w7,
                             char* __restrict__ ws) {
  int tid = blockIdx.x * 256 + threadIdx.x;
  // w0 tiles: 13*128*64 fp16 elements
  if (tid < 13 * 128 * 64) {
    int t = tid >> 13;            // tile (k/64)
    int rem = tid & 8191;
    int n = rem >> 6, kk = rem & 63;
    int k = t * 64 + kk;
    float v = (n < 124 && k < 784) ? w0[n * 784 + k] : 0.f;
    int off = t * 16384 + n * 128 + ((kk * 2) ^ ((n & 7) << 4));
    *(__half*)(ws + off) = __float2half(v);
    return;
  }
  int r = tid - 13 * 128 * 64;
  if (r < 32 * 128) {             // w1 padded [32][128]
    int n = r >> 7, k = r & 127;
    float v = (k < 124) ? w1[n * 124 + k] : 0.f;
    int off = W1P_OFF + n * 256 + ((k * 2) ^ ((n & 7) << 4));
    *(__half*)(ws + off) = __float2half(v);
    return;
  }
  r -= 32 * 128;
  if (r < 704) { ((float*)(ws + SW_OFF))[r] = w3[r]; return; }                 // w3 [22][32]
  r -= 704;
  if (r < 504) {                                                               // w5 [21][24]
    int n = r / 24, k = r % 24;
    ((float*)(ws + SW_OFF + 2816))[r] = (k < 22) ? w5[n * 22 + k] : 0.f;
    return;
  }
  r -= 504;
  if (r < 240) {                                                               // w7 [10][24]
    int n = r / 24, k = r % 24;
    ((float*)(ws + SW_OFF + 4832))[r] = (k < 21) ? w7[n * 21 + k] : 0.f;
    return;
  }
  r -= 240;
  if (r < 24) { ((float*)(ws + SW_OFF + 5792))[r] = (r < 22) ? b3[r] : 0.f; return; }
  r -= 24;
  if (r < 24) { ((float*)(ws + SW_OFF + 5888))[r] = (r < 21) ? b5[r] : 0.f; return; }
}

// ============ fused MLP forward ============
__global__ __launch_bounds__(256, 2) void fused_mlp(
    const float* __restrict__ x, const char* __restrict__ wsg,
    float* __restrict__ out) {
  __shared__ char sm[LDS_BYTES];
  const int tid  = threadIdx.x;
  const int lane = tid & 63;
  const int wave = tid >> 6;
  const int row0 = blockIdx.x << 7;          // 128 rows per block

  // one-time LDS copies: w1p (8192B) + small fp32 block (5984B)
  {
    const uint4* s1 = (const uint4*)(wsg + W1P_OFF);
    uint4* d1 = (uint4*)(sm + L_W1);
#pragma unroll
    for (int i = 0; i < 2; i++) d1[tid + 256 * i] = s1[tid + 256 * i];
    const uint* s2 = (const uint*)(wsg + SW_OFF);
    uint* d2 = (uint*)(sm + L_SW);
    for (int i = tid; i < SW_BYTES / 4; i += 256) d2[i] = s2[i];
  }

  // ---------------- phase 0: layer 0 GEMM (M=128, N=128pad, K=13x64) ----------------
  f32x4 acc[2][8];
#pragma unroll
  for (int m = 0; m < 2; m++)
#pragma unroll
    for (int n = 0; n < 8; n++) acc[m][n] = f32x4{0.f, 0.f, 0.f, 0.f};

  const int xrow = tid >> 4;     // 0..15
  const int xc4  = tid & 15;     // float4 column
  float4 xr[8];
  uint4  wr[4];

  // prologue: stage tile 0 into regs
  {
#pragma unroll
    for (int i = 0; i < 8; i++)
      xr[i] = *(const float4*)(x + (size_t)(row0 + xrow + i * 16) * 784 + xc4 * 4);
    const uint4* wsrc = (const uint4*)(wsg + W0T_OFF);
#pragma unroll
    for (int j = 0; j < 4; j++) wr[j] = wsrc[tid + j * 256];
  }

  const int a_r  = (wave << 5) + (lane & 15);   // wave's 32-row strip, + mf*16
  const int kg16 = (lane >> 4) << 4;            // byte offset of 8-elem k group

  for (int t = 0; t < 13; t++) {
    __syncthreads();   // staging buffers free (prev MFMA done), regs(t) arrived
    // store staged tile t (fp32 -> fp16 for x; w already fp16+swizzled)
#pragma unroll
    for (int i = 0; i < 8; i++) {
      const int rr = xrow + i * 16;
      __half2 p0 = __float22half2_rn(make_float2(xr[i].x, xr[i].y));
      __half2 p1 = __float22half2_rn(make_float2(xr[i].z, xr[i].w));
      uint2 pk = make_uint2(__builtin_bit_cast(unsigned, p0),
                            __builtin_bit_cast(unsigned, p1));
      *(uint2*)(sm + L_XS + rr * 128 + ((xc4 * 8) ^ ((rr & 7) << 4))) = pk;
    }
    {
      uint4* wd = (uint4*)(sm + L_WS);
#pragma unroll
      for (int j = 0; j < 4; j++) wd[tid + j * 256] = wr[j];
    }
    // prefetch tile t+1 into regs (stays in flight across the raw barrier)
    if (t + 1 < 13) {
      const int k0 = (t + 1) * 64 + xc4 * 4;
      if (k0 < 784) {
#pragma unroll
        for (int i = 0; i < 8; i++)
          xr[i] = *(const float4*)(x + (size_t)(row0 + xrow + i * 16) * 784 + k0);
      } else {
#pragma unroll
        for (int i = 0; i < 8; i++) xr[i] = make_float4(0.f, 0.f, 0.f, 0.f);
      }
      const uint4* wsrc = (const uint4*)(wsg + W0T_OFF + (t + 1) * 16384);
#pragma unroll
      for (int j = 0; j < 4; j++) wr[j] = wsrc[tid + j * 256];
    }
    asm volatile("s_waitcnt lgkmcnt(0)" ::: "memory");  // ds_writes visible
    __builtin_amdgcn_s_barrier();                       // raw: no vmcnt drain
    __builtin_amdgcn_sched_barrier(0);
    // MFMA on tile t
#pragma unroll
    for (int kf = 0; kf < 2; kf++) {
      half8 af[2], bf[8];
#pragma unroll
      for (int mf = 0; mf < 2; mf++) {
        const int rr = a_r + mf * 16;
        af[mf] = *(const half8*)(sm + L_XS + rr * 128 +
                                 ((kf * 64 + kg16) ^ ((rr & 7) << 4)));
      }
#pragma unroll
      for (int nf = 0; nf < 8; nf++) {
        const int nn = nf * 16 + (lane & 15);
        bf[nf] = *(const half8*)(sm + L_WS + nn * 128 +
                                 ((kf * 64 + kg16) ^ ((nn & 7) << 4)));
      }
#pragma unroll
      for (int mf = 0; mf < 2; mf++)
#pragma unroll
        for (int nf = 0; nf < 8; nf++)
          acc[mf][nf] = __builtin_amdgcn_mfma_f32_16x16x32_f16(
              af[mf], bf[nf], acc[mf][nf], 0, 0, 0);
    }
  }

  // ---------------- phase 1: h0 -> LDS fp16 (swizzled), reuses staging region ----------------
  __syncthreads();   // all waves done reading XS/WS
#pragma unroll
  for (int mf = 0; mf < 2; mf++) {
    const int rb = (wave << 5) + mf * 16 + ((lane >> 4) << 2);
#pragma unroll
    for (int nf = 0; nf < 8; nf++) {
      const int cc = nf * 16 + (lane & 15);
#pragma unroll
      for (int q = 0; q < 4; q++) {
        const int rr = rb + q;
        *(__half*)(sm + L_H0 + rr * 256 + ((cc * 2) ^ ((rr & 7) << 4))) =
            __float2half(acc[mf][nf][q]);
      }
    }
  }
  __syncthreads();

  // ---------------- phase 2: layer 1 (M=128, N=32, K=128pad) + relu ----------------
  f32x4 acc1[2][2];
#pragma unroll
  for (int m = 0; m < 2; m++) {
    acc1[m][0] = f32x4{0.f, 0.f, 0.f, 0.f};
    acc1[m][1] = f32x4{0.f, 0.f, 0.f, 0.f};
  }
#pragma unroll
  for (int kf = 0; kf < 4; kf++) {
    half8 a1[2], b1[2];
#pragma unroll
    for (int mf = 0; mf < 2; mf++) {
      const int rr = a_r + mf * 16;
      a1[mf] = *(const half8*)(sm + L_H0 + rr * 256 +
                               ((kf * 64 + kg16) ^ ((rr & 7) << 4)));
    }
#pragma unroll
    for (int nf = 0; nf < 2; nf++) {
      const int nn = nf * 16 + (lane & 15);
      b1[nf] = *(const half8*)(sm + L_W1 + nn * 256 +
                               ((kf * 64 + kg16) ^ ((nn & 7) << 4)));
    }
#pragma unroll
    for (int mf = 0; mf < 2; mf++)
#pragma unroll
      for (int nf = 0; nf < 2; nf++)
        acc1[mf][nf] = __builtin_amdgcn_mfma_f32_16x16x32_f16(
            a1[mf], b1[nf], acc1[mf][nf], 0, 0, 0);
  }
#pragma unroll
  for (int mf = 0; mf < 2; mf++) {
    const int rb = (wave << 5) + mf * 16 + ((lane >> 4) << 2);
#pragma unroll
    for (int nf = 0; nf < 2; nf++) {
      const int cc = nf * 16 + (lane & 15);
#pragma unroll
      for (int q = 0; q < 4; q++) {
        const int rr = rb + q;
        float v = fmaxf(acc1[mf][nf][q], 0.f);
        *(__half*)(sm + L_H1 + rr * 64 + ((cc * 2) ^ (((rr >> 1) & 3) << 4))) =
            __float2half(v);
      }
    }
  }
  __syncthreads();

  // ---------------- phase 3: layers 3,5,7 + log_softmax (fp32, 2 threads/row) ----------------
  const int r = tid & 127;
  const int j = tid >> 7;
  float h1r[32];
#pragma unroll
  for (int kc = 0; kc < 4; kc++) {
    half8 v = *(const half8*)(sm + L_H1 + r * 64 +
                              ((kc * 16) ^ (((r >> 1) & 3) << 4)));
#pragma unroll
    for (int e = 0; e < 8; e++) h1r[kc * 8 + e] = (float)v[e];
  }
  const float* w3p = (const float*)(sm + L_SW);
  const float* w5p = (const float*)(sm + L_SW + 2816);
  const float* w7p = (const float*)(sm + L_SW + 4832);
  const float* b3p = (const float*)(sm + L_SW + 5792);
  const float* b5p = (const float*)(sm + L_SW + 5888);
  float* h3l = (float*)(sm + L_H3);
  float* h5l = (float*)(sm + L_H5);

#pragma unroll
  for (int i = 0; i < 11; i++) {   // layer 3: n = j, j+2, ...
    const int n = j + 2 * i;
    float s = b3p[n];
#pragma unroll
    for (int k = 0; k < 32; k++) s += h1r[k] * w3p[n * 32 + k];
    h3l[r * 25 + n] = fmaxf(s, 0.f);
  }
  __syncthreads();
  float h3r[22];
#pragma unroll
  for (int k = 0; k < 22; k++) h3r[k] = h3l[r * 25 + k];
#pragma unroll
  for (int i = 0; i < 11; i++) {   // layer 5
    const int n = j + 2 * i;
    if (n < 21) {
      float s = b5p[n];
#pragma unroll
      for (int k = 0; k < 22; k++) s += h3r[k] * w5p[n * 24 + k];
      h5l[r * 25 + n] = fmaxf(s, 0.f);
    }
  }
  __syncthreads();
  if (j == 0) {                    // layer 7 + log_softmax, one thread/row
    float h5r[21];
#pragma unroll
    for (int k = 0; k < 21; k++) h5r[k] = h5l[r * 25 + k];
    float lg[10];
    float mx = -3.4e38f;
#pragma unroll
    for (int n = 0; n < 10; n++) {
      float s = 0.f;
#pragma unroll
      for (int k = 0; k < 21; k++) s += h5r[k] * w7p[n * 24 + k];
      lg[n] = s;
      mx = fmaxf(mx, s);
    }
    float se = 0.f;
#pragma unroll
    for (int n = 0; n < 10; n++) se += __expf(lg[n] - mx);
    const float lse = mx + __logf(se);
    float* op = out + (size_t)(row0 + r) * 10;
#pragma unroll
    for (int n = 0; n < 10; n++) op[n] = lg[n] - lse;
  }
}

extern "C" void kernel_launch(void* const* d_in, const int* in_sizes, int n_in,
                              void* d_out, int out_size, void* d_ws, size_t ws_size,
                              hipStream_t stream) {
  const float* x  = (const float*)d_in[0];
  const float* w0 = (const float*)d_in[1];
  const float* w1 = (const float*)d_in[2];
  const float* w3 = (const float*)d_in[3];
  const float* b3 = (const float*)d_in[4];
  const float* w5 = (const float*)d_in[5];
  const float* b5 = (const float*)d_in[6];
  const float* w7 = (const float*)d_in[7];
  float* out = (float*)d_out;
  char* ws = (char*)d_ws;

  const int prep_elems = 13 * 128 * 64 + 32 * 128 + 704 + 504 + 240 + 24 + 24;
  prep_weights<<<(prep_elems + 255) / 256, 256, 0, stream>>>(w0, w1, w3, b3, w5,
                                                             b5, w7, ws);
  fused_mlp<<<65536 / 128, 256, 0, stream>>>(x, ws, out);
}

// Round 3
// 57.315 us; speedup vs baseline: 1.0750x; 1.0750x over previous
//
#include <hip/hip_runtime.h>
#include <hip/hip_fp16.h>

typedef _Float16 half8 __attribute__((ext_vector_type(8)));
typedef __fp16 cvt2_t __attribute__((ext_vector_type(2)));
typedef float f32x4 __attribute__((ext_vector_type(4)));

// ---------------- workspace layout (bytes) ----------------
// W0F: fragment-ordered w0 fp16: linear uint4 index = t*1024 + kf*512 + nf*64 + l
//      element e of lane l = w0[n=nf*16+(l&15)][k=t*64+kf*32+(l>>4)*8+e], zero-padded
#define W0F_UNITS (13 * 1024)              // uint4 units
#define W1F_OFF   (W0F_UNITS * 16)         // 212992
#define W1F_UNITS 512                      // kf*128 + nf*64 + l
#define SW_OFF    (W1F_OFF + W1F_UNITS * 16)  // 221184
// SW (fp32): w3[22*32] @0 | w5p[21][24] @2816B | w7p[10][24] @4832B | b3 @5792B | b5 @5888B

// ---------------- LDS (per 1-wave block) ----------------
#define L_H0   0        // [32 r][128 c] half, byte = r*256 + (2c ^ ((r&7)<<4))  (8192 B)
#define L_H1   8192     // [32 r][32 c]  half, byte = r*64  + (2c ^ ((r&3)<<4))  (2048 B)
#define L_H3   0        // [32][25] f32 (3200 B)  -- overlays H0 after phase 2
#define L_H5   3200     // [32][25] f32 (3200 B)
#define L_OS   6400     // [320] f32 out staging (1280 B)
#define LDS_SZ 10240

// ============ prep: rearrange weights into fragment order ============
__global__ void prep_weights(const float* __restrict__ w0,
                             const float* __restrict__ w1,
                             const float* __restrict__ w3,
                             const float* __restrict__ b3,
                             const float* __restrict__ w5,
                             const float* __restrict__ b5,
                             const float* __restrict__ w7,
                             char* __restrict__ ws) {
  int tid = blockIdx.x * 256 + threadIdx.x;
  if (tid < W0F_UNITS) {
    int t  = tid >> 10;
    int kf = (tid >> 9) & 1;
    int nf = (tid >> 6) & 7;
    int l  = tid & 63;
    int n  = nf * 16 + (l & 15);
    int k0 = t * 64 + kf * 32 + (l >> 4) * 8;
    alignas(16) __half h[8];
#pragma unroll
    for (int e = 0; e < 8; e++) {
      int k = k0 + e;
      h[e] = __float2half((n < 124 && k < 784) ? w0[n * 784 + k] : 0.f);
    }
    *(uint4*)(ws + tid * 16) = *(const uint4*)h;
    return;
  }
  int r = tid - W0F_UNITS;
  if (r < W1F_UNITS) {
    int kf = r >> 7;
    int nf = (r >> 6) & 1;
    int l  = r & 63;
    int n  = nf * 16 + (l & 15);
    int k0 = kf * 32 + (l >> 4) * 8;
    alignas(16) __half h[8];
#pragma unroll
    for (int e = 0; e < 8; e++) {
      int k = k0 + e;
      h[e] = __float2half((k < 124) ? w1[n * 124 + k] : 0.f);
    }
    *(uint4*)(ws + W1F_OFF + r * 16) = *(const uint4*)h;
    return;
  }
  r -= W1F_UNITS;
  float* sw = (float*)(ws + SW_OFF);
  if (r < 704) { sw[r] = w3[r]; return; }                     // w3 [22][32]
  r -= 704;
  if (r < 504) {                                              // w5 [21][24]
    int n = r / 24, k = r % 24;
    sw[704 + r] = (k < 22) ? w5[n * 22 + k] : 0.f;
    return;
  }
  r -= 504;
  if (r < 240) {                                              // w7 [10][24]
    int n = r / 24, k = r % 24;
    sw[1208 + r] = (k < 21) ? w7[n * 21 + k] : 0.f;
    return;
  }
  r -= 240;
  if (r < 24) { sw[1448 + r] = (r < 22) ? b3[r] : 0.f; return; }
  r -= 24;
  if (r < 24) { sw[1472 + r] = (r < 21) ? b5[r] : 0.f; return; }
}

// ============ fused MLP: 1 wave = 32 rows, no barriers in hot loop ============
__device__ __forceinline__ half8 cvt8(const float4& a, const float4& b) {
  cvt2_t p0 = __builtin_amdgcn_cvt_pkrtz(a.x, a.y);
  cvt2_t p1 = __builtin_amdgcn_cvt_pkrtz(a.z, a.w);
  cvt2_t p2 = __builtin_amdgcn_cvt_pkrtz(b.x, b.y);
  cvt2_t p3 = __builtin_amdgcn_cvt_pkrtz(b.z, b.w);
  uint4 u;
  u.x = __builtin_bit_cast(unsigned, p0);
  u.y = __builtin_bit_cast(unsigned, p1);
  u.z = __builtin_bit_cast(unsigned, p2);
  u.w = __builtin_bit_cast(unsigned, p3);
  return __builtin_bit_cast(half8, u);
}

__global__ __launch_bounds__(64, 2) void fused_mlp(
    const float* __restrict__ x, const char* __restrict__ ws,
    float* __restrict__ out) {
  __shared__ alignas(16) char sm[LDS_SZ];
  const int l  = threadIdx.x;
  const int lr = l & 15;
  const int lg = l >> 4;
  const size_t row0 = (size_t)blockIdx.x * 32;

  const float* xb0 = x + (row0 + lr) * 784;
  const float* xb1 = xb0 + 16 * 784;

  f32x4 acc[2][8];
#pragma unroll
  for (int mf = 0; mf < 2; mf++)
#pragma unroll
    for (int nf = 0; nf < 8; nf++) acc[mf][nf] = f32x4{0.f, 0.f, 0.f, 0.f};

  const uint4* wf = (const uint4*)ws;

  float4 xA[2][2][2], xB[2][2][2];   // [mf][kf][half4]

  // prologue: tile 0 -> xA
#pragma unroll
  for (int mf = 0; mf < 2; mf++)
#pragma unroll
    for (int kf = 0; kf < 2; kf++) {
      const float* p = (mf ? xb1 : xb0) + kf * 32 + lg * 8;
      xA[mf][kf][0] = *(const float4*)p;
      xA[mf][kf][1] = *(const float4*)(p + 4);
    }

  // Per-tile body: load B-frags(T), cvt XC, prefetch tile T+1 into XN, MFMA.
#define TILE_BODY(T, XC, XN, PF_FULL)                                          \
  {                                                                            \
    half8 bf[2][8];                                                            \
    _Pragma("unroll") for (int kf = 0; kf < 2; kf++)                           \
        _Pragma("unroll") for (int nf = 0; nf < 8; nf++)                       \
            bf[kf][nf] = __builtin_bit_cast(                                   \
                half8, wf[(T) * 1024 + kf * 512 + nf * 64 + l]);               \
    half8 af[2][2];                                                            \
    _Pragma("unroll") for (int mf = 0; mf < 2; mf++)                           \
        _Pragma("unroll") for (int kf = 0; kf < 2; kf++)                       \
            af[mf][kf] = cvt8(XC[mf][kf][0], XC[mf][kf][1]);                   \
    if (PF_FULL) {                                                             \
      _Pragma("unroll") for (int mf = 0; mf < 2; mf++)                         \
          _Pragma("unroll") for (int kf = 0; kf < 2; kf++) {                   \
        const float* p = (mf ? xb1 : xb0) + ((T) + 1) * 64 + kf * 32 + lg * 8; \
        XN[mf][kf][0] = *(const float4*)p;                                     \
        XN[mf][kf][1] = *(const float4*)(p + 4);                               \
      }                                                                        \
    } else { /* prefetch tile 12: k=768..784, kf=0, lg<2 only */               \
      const float4 z = {0.f, 0.f, 0.f, 0.f};                                   \
      _Pragma("unroll") for (int mf = 0; mf < 2; mf++) {                       \
        const float* p = (mf ? xb1 : xb0) + 768 + lg * 8;                      \
        bool v = (lg < 2);                                                     \
        XN[mf][0][0] = v ? *(const float4*)p : z;                              \
        XN[mf][0][1] = v ? *(const float4*)(p + 4) : z;                        \
        XN[mf][1][0] = z;                                                      \
        XN[mf][1][1] = z;                                                      \
      }                                                                        \
    }                                                                          \
    _Pragma("unroll") for (int kf = 0; kf < 2; kf++)                           \
        _Pragma("unroll") for (int mf = 0; mf < 2; mf++)                       \
            _Pragma("unroll") for (int nf = 0; nf < 8; nf++)                   \
                acc[mf][nf] = __builtin_amdgcn_mfma_f32_16x16x32_f16(          \
                    af[mf][kf], bf[kf][nf], acc[mf][nf], 0, 0, 0);             \
  }

  TILE_BODY(0, xA, xB, 1)
  TILE_BODY(1, xB, xA, 1)
  TILE_BODY(2, xA, xB, 1)
  TILE_BODY(3, xB, xA, 1)
  TILE_BODY(4, xA, xB, 1)
  TILE_BODY(5, xB, xA, 1)
  TILE_BODY(6, xA, xB, 1)
  TILE_BODY(7, xB, xA, 1)
  TILE_BODY(8, xA, xB, 1)
  TILE_BODY(9, xB, xA, 1)
  TILE_BODY(10, xA, xB, 1)
  TILE_BODY(11, xB, xA, 0)   // prefetches tile 12 (partial) into xA

  // tail tile 12: kf=0 only (k 768..784; invalid lanes hold zeros)
  {
    half8 bf[8];
#pragma unroll
    for (int nf = 0; nf < 8; nf++)
      bf[nf] = __builtin_bit_cast(half8, wf[12 * 1024 + nf * 64 + l]);
    half8 af[2];
#pragma unroll
    for (int mf = 0; mf < 2; mf++) af[mf] = cvt8(xA[mf][0][0], xA[mf][0][1]);
#pragma unroll
    for (int mf = 0; mf < 2; mf++)
#pragma unroll
      for (int nf = 0; nf < 8; nf++)
        acc[mf][nf] = __builtin_amdgcn_mfma_f32_16x16x32_f16(
            af[mf], bf[nf], acc[mf][nf], 0, 0, 0);
  }

  // issue w1 fragment loads early (consumed in phase 2, hides L2 latency)
  half8 b1[4][2];
  {
    const uint4* w1f = (const uint4*)(ws + W1F_OFF);
#pragma unroll
    for (int kf = 0; kf < 4; kf++)
#pragma unroll
      for (int nf = 0; nf < 2; nf++)
        b1[kf][nf] = __builtin_bit_cast(half8, w1f[kf * 128 + nf * 64 + l]);
  }

  // ---- phase 1: h0 (fp32 acc, no activation) -> LDS fp16, swizzled ----
#pragma unroll
  for (int mf = 0; mf < 2; mf++)
#pragma unroll
    for (int nf = 0; nf < 8; nf++)
#pragma unroll
      for (int q = 0; q < 4; q++) {
        int rr = mf * 16 + lg * 4 + q;
        int cc = nf * 16 + lr;
        *(__half*)(sm + L_H0 + rr * 256 + ((2 * cc) ^ ((rr & 7) << 4))) =
            __float2half(acc[mf][nf][q]);
      }
  __syncthreads();   // 1-wave block: cheap

  // ---- phase 2: layer 1 (N=32, K=128pad) + relu -> h1 ----
  f32x4 acc1[2][2];
#pragma unroll
  for (int mf = 0; mf < 2; mf++) {
    acc1[mf][0] = f32x4{0.f, 0.f, 0.f, 0.f};
    acc1[mf][1] = f32x4{0.f, 0.f, 0.f, 0.f};
  }
#pragma unroll
  for (int kf = 0; kf < 4; kf++) {
    half8 a1[2];
#pragma unroll
    for (int mf = 0; mf < 2; mf++) {
      int rr = mf * 16 + lr;
      int cb = kf * 64 + lg * 16;   // byte offset of k-group
      a1[mf] = *(const half8*)(sm + L_H0 + rr * 256 + (cb ^ ((rr & 7) << 4)));
    }
#pragma unroll
    for (int mf = 0; mf < 2; mf++)
#pragma unroll
      for (int nf = 0; nf < 2; nf++)
        acc1[mf][nf] = __builtin_amdgcn_mfma_f32_16x16x32_f16(
            a1[mf], b1[kf][nf], acc1[mf][nf], 0, 0, 0);
  }
#pragma unroll
  for (int mf = 0; mf < 2; mf++)
#pragma unroll
    for (int nf = 0; nf < 2; nf++)
#pragma unroll
      for (int q = 0; q < 4; q++) {
        int rr = mf * 16 + lg * 4 + q;
        int cc = nf * 16 + lr;
        float v = fmaxf(acc1[mf][nf][q], 0.f);
        *(__half*)(sm + L_H1 + rr * 64 + ((2 * cc) ^ ((rr & 3) << 4))) =
            __float2half(v);
      }
  __syncthreads();

  // ---- phase 3: layers 3,5,7 + log_softmax (fp32, 2 lanes per row) ----
  const int r = l & 31;
  const int j = l >> 5;
  float h1v[32];
#pragma unroll
  for (int cb = 0; cb < 4; cb++) {
    half8 v = *(const half8*)(sm + L_H1 + r * 64 + ((cb * 16) ^ ((r & 3) << 4)));
#pragma unroll
    for (int e = 0; e < 8; e++) h1v[cb * 8 + e] = (float)v[e];
  }
  const float* w3g = (const float*)(ws + SW_OFF);
  const float* w5g = (const float*)(ws + SW_OFF + 2816);
  const float* w7g = (const float*)(ws + SW_OFF + 4832);
  const float* b3g = (const float*)(ws + SW_OFF + 5792);
  const float* b5g = (const float*)(ws + SW_OFF + 5888);
  float* h3l = (float*)(sm + L_H3);
  float* h5l = (float*)(sm + L_H5);

#pragma unroll
  for (int i = 0; i < 11; i++) {
    int n = j + 2 * i;
    float s = b3g[n];
    const float4* wrow = (const float4*)(w3g + n * 32);
#pragma unroll
    for (int kk = 0; kk < 8; kk++) {
      float4 wv = wrow[kk];
      s += h1v[4 * kk] * wv.x + h1v[4 * kk + 1] * wv.y +
           h1v[4 * kk + 2] * wv.z + h1v[4 * kk + 3] * wv.w;
    }
    h3l[r * 25 + n] = fmaxf(s, 0.f);
  }
  __syncthreads();
  float h3v[24];
#pragma unroll
  for (int k = 0; k < 24; k++) h3v[k] = (k < 22) ? h3l[r * 25 + k] : 0.f;
#pragma unroll
  for (int i = 0; i < 11; i++) {
    int n = j + 2 * i;
    if (n < 21) {
      float s = b5g[n];
      const float4* wrow = (const float4*)(w5g + n * 24);
#pragma unroll
      for (int kk = 0; kk < 6; kk++) {
        float4 wv = wrow[kk];
        s += h3v[4 * kk] * wv.x + h3v[4 * kk + 1] * wv.y +
             h3v[4 * kk + 2] * wv.z + h3v[4 * kk + 3] * wv.w;
      }
      h5l[r * 25 + n] = fmaxf(s, 0.f);
    }
  }
  __syncthreads();
  if (j == 0) {
    float h5v[24];
#pragma unroll
    for (int k = 0; k < 24; k++) h5v[k] = (k < 21) ? h5l[r * 25 + k] : 0.f;
    float lgt[10];
    float mx = -3.4e38f;
#pragma unroll
    for (int n = 0; n < 10; n++) {
      float s = 0.f;
      const float4* wrow = (const float4*)(w7g + n * 24);
#pragma unroll
      for (int kk = 0; kk < 6; kk++) {
        float4 wv = wrow[kk];
        s += h5v[4 * kk] * wv.x + h5v[4 * kk + 1] * wv.y +
             h5v[4 * kk + 2] * wv.z + h5v[4 * kk + 3] * wv.w;
      }
      lgt[n] = s;
      mx = fmaxf(mx, s);
    }
    float se = 0.f;
#pragma unroll
    for (int n = 0; n < 10; n++) se += __expf(lgt[n] - mx);
    const float lse = mx + __logf(se);
    float* os = (float*)(sm + L_OS);
#pragma unroll
    for (int n = 0; n < 10; n++) os[r * 10 + n] = lgt[n] - lse;
  }
  __syncthreads();
  {
    const float* os = (const float*)(sm + L_OS);
#pragma unroll
    for (int i = 0; i < 5; i++) out[row0 * 10 + i * 64 + l] = os[i * 64 + l];
  }
}

extern "C" void kernel_launch(void* const* d_in, const int* in_sizes, int n_in,
                              void* d_out, int out_size, void* d_ws, size_t ws_size,
                              hipStream_t stream) {
  const float* x  = (const float*)d_in[0];
  const float* w0 = (const float*)d_in[1];
  const float* w1 = (const float*)d_in[2];
  const float* w3 = (const float*)d_in[3];
  const float* b3 = (const float*)d_in[4];
  const float* w5 = (const float*)d_in[5];
  const float* b5 = (const float*)d_in[6];
  const float* w7 = (const float*)d_in[7];
  float* out = (float*)d_out;
  char* ws = (char*)d_ws;

  const int prep_threads = W0F_UNITS + W1F_UNITS + 704 + 504 + 240 + 24 + 24;
  prep_weights<<<(prep_threads + 255) / 256, 256, 0, stream>>>(w0, w1, w3, b3,
                                                               w5, b5, w7, ws);
  fused_mlp<<<65536 / 32, 64, 0, stream>>>(x, ws, out);
}